// Round 1
// baseline (803.239 us; speedup 1.0000x reference)
//
#include <hip/hip_runtime.h>

// SqueezeLayer: checkerboard space-to-depth.
// in : x[8][64][512][512] fp32
// out: y[8][256][256][256] fp32, y[b][4c+2kh+kw][h2][w2] = x[b][c][2h2+kh][2w2+kw]
//
// Pure memory-bound permutation: 512 MiB in + 512 MiB out.
// Each thread: one float4 load (w=4t..4t+3 of one input row) ->
// two float2 stores (w2=2t,2t+1 of the kw=0 and kw=1 output rows).
// All accesses fully coalesced; index math is shifts/masks only.

__global__ __launch_bounds__(256) void squeeze_kernel(
    const float* __restrict__ x, float* __restrict__ out) {
    // Flat float4 index over the input. Total = 8*64*512*512/4 = 33,554,432.
    unsigned int idx = blockIdx.x * blockDim.x + threadIdx.x;

    // Decompose: idx = (((b*64 + c)*512 + h)*128 + w4)
    unsigned int w4  = idx & 127u;          // W/4 = 128
    unsigned int row = idx >> 7;
    unsigned int h   = row & 511u;          // H = 512
    unsigned int bc  = row >> 9;
    unsigned int c   = bc & 63u;            // C = 64
    unsigned int b   = bc >> 6;
    unsigned int h2  = h >> 1;
    unsigned int kh  = h & 1u;

    const float4 v = ((const float4*)x)[idx];

    // out flat base: ((b*256 + 4c + 2kh)*256 + h2)*256 + 2*w4
    unsigned int c4 = (c << 2) + (kh << 1);            // kw = 0 channel
    unsigned int ob = (((b << 8) + c4) << 8 | h2) << 8 | (w4 << 1);

    // kw=0 row: even input w -> (v.x, v.z); kw=1 row (+H2*W2 floats): (v.y, v.w)
    *(float2*)(out + ob)          = make_float2(v.x, v.z);
    *(float2*)(out + ob + 65536u) = make_float2(v.y, v.w);
}

extern "C" void kernel_launch(void* const* d_in, const int* in_sizes, int n_in,
                              void* d_out, int out_size, void* d_ws, size_t ws_size,
                              hipStream_t stream) {
    const float* x = (const float*)d_in[0];
    float* out = (float*)d_out;

    // n4 = 8*64*512*512 / 4 = 33,554,432 float4s; 256 threads/block.
    const unsigned int n4 = 33554432u;
    const unsigned int block = 256u;
    const unsigned int grid = n4 / block;  // 131072, exact

    squeeze_kernel<<<grid, block, 0, stream>>>(x, out);
}